// Round 9
// baseline (256.101 us; speedup 1.0000x reference)
//
#include <hip/hip_runtime.h>
#include <math.h>

#define NTOK   16384
#define HDIM   1024
#define HHALF  512
#define NE     16

// d_out layout (concatenated reference outputs, all f32; indices stored as float)
#define OFF_TP  0
#define OFF_TI  (NTOK * 2)
#define OFF_DEC (NTOK * 4)
#define OFF_PH  (OFF_DEC + NTOK * NE)
#define OFF_PR  (OFF_PH + NTOK * NE)

typedef _Float16 half8 __attribute__((ext_vector_type(8)));
typedef _Float16 half4 __attribute__((ext_vector_type(4)));
typedef short    bf16x8 __attribute__((ext_vector_type(8)));
typedef float f32x16 __attribute__((ext_vector_type(16)));
typedef float f32x4 __attribute__((ext_vector_type(4)));

typedef __attribute__((address_space(3))) void lds_void_t;
typedef const __attribute__((address_space(1))) void gbl_void_t;

#define LO_SCALE     2048.0f
#define LO_SCALE_INV (1.0f / 2048.0f)
#define MFMA_F16(a,b,c)  __builtin_amdgcn_mfma_f32_32x32x16_f16(a,b,c,0,0,0)
#define MFMA_BF16(a,b,c) __builtin_amdgcn_mfma_f32_32x32x16_bf16(a,b,c,0,0,0)
#define MFMA16(a,b,c)    __builtin_amdgcn_mfma_f32_16x16x32_f16(a,b,c,0,0,0)

// lgkm-only barrier: LDS visibility; vmcnt handled by explicit counted waits.
#define BAR() asm volatile("s_waitcnt lgkmcnt(0)\n\ts_barrier" ::: "memory")
#define SB()  __builtin_amdgcn_sched_barrier(0)

// ws image layout (f16/short units):
//   [0, 2097152)            B-LDS image: per (ph,hk): 16384 f16 = 32KB block,
//                           addr16 = ((ph*64+hk)*16384) + (c32*2+pl)*512 + l*8
//                           pl=0: f16(w) bits; pl=1: bf16(w - f16(w)) bits
//   [2097152, 3145728)      wllo frag image: addr16 = 2097152 +
//                           ((ph*64+hk)*16 + c32)*512 + l*8 ; bf16 bits of
//                           (w - wh - wlo_b)
#define WSB_PER_PH  (64 * 16384)
#define WSL_BASE    2097152
#define WSL_PER_PH  (64 * 8192)
#define WS_BYTES    ((size_t)(2097152 + 1048576) * 2)

__device__ __forceinline__ float gelu_exact(float x) {
    return 0.5f * x * (1.0f + erff(x * 0.70710678118654752440f));
}

__device__ __forceinline__ short f32_to_bf16_bits(float f) {
    unsigned u = __builtin_bit_cast(unsigned, f);
    u += 0x7FFFu + ((u >> 16) & 1u);
    return (short)(u >> 16);
}
__device__ __forceinline__ float bf16_bits_to_f32(short s) {
    unsigned u = ((unsigned)(unsigned short)s) << 16;
    return __builtin_bit_cast(float, u);
}
__device__ __forceinline__ bf16x8 cvt_h2b(half8 h) {
    bf16x8 r;
    #pragma unroll
    for (int j = 0; j < 8; ++j) r[j] = f32_to_bf16_bits((float)h[j]);
    return r;
}
// x -> (f16(x)*2048 [exact], f16((x-f16(x))*2048))
__device__ __forceinline__ void cvt_splitQ(float4 v, half4& hi, half4& lo) {
    _Float16 h0 = (_Float16)v.x, h1 = (_Float16)v.y,
             h2 = (_Float16)v.z, h3 = (_Float16)v.w;
    const _Float16 S = (_Float16)2048.0f;
    hi = (half4){(_Float16)(h0 * S), (_Float16)(h1 * S),
                 (_Float16)(h2 * S), (_Float16)(h3 * S)};
    lo = (half4){(_Float16)((v.x - (float)h0) * LO_SCALE),
                 (_Float16)((v.y - (float)h1) * LO_SCALE),
                 (_Float16)((v.z - (float)h2) * LO_SCALE),
                 (_Float16)((v.w - (float)h3) * LO_SCALE)};
}

// ---------------------------------------------------------------------------
// Prologue: build the two W images in ws (no output zeroing needed -- gemm
// writes raw sums directly, single writer per element).
// ---------------------------------------------------------------------------
__global__ void __launch_bounds__(256)
qir_wtrans(const float* __restrict__ w1a, const float* __restrict__ w1p,
           _Float16* __restrict__ wt)
{
    int u = blockIdx.x * 256 + threadIdx.x;     // 0..393215
    short* wt16 = (short*)wt;
    if (u < 262144) {
        // wh / wlo_b planes
        int l   = u & 63;
        int pl  = (u >> 6) & 1;
        int c32 = (u >> 7) & 15;
        int hk  = (u >> 11) & 63;
        int ph  = u >> 17;
        int col = c32 * 32 + (l & 31);
        int k0  = hk * 16 + (l >> 5) * 8;
        const float* __restrict__ W = ph ? w1p : w1a;
        short v[8];
        #pragma unroll
        for (int j = 0; j < 8; ++j) {
            float x = W[(size_t)(k0 + j) * HHALF + col];
            _Float16 h = (_Float16)x;
            if (pl == 0) v[j] = __builtin_bit_cast(short, h);
            else         v[j] = f32_to_bf16_bits(x - (float)h);
        }
        #pragma unroll
        for (int j = 0; j < 8; ++j) wt16[(size_t)u * 8 + j] = v[j];
    } else {
        int u2  = u - 262144;                   // 0..131071
        int l   = u2 & 63;
        int c32 = (u2 >> 6) & 15;
        int hk  = (u2 >> 10) & 63;
        int ph  = u2 >> 16;
        int col = c32 * 32 + (l & 31);
        int k0  = hk * 16 + (l >> 5) * 8;
        const float* __restrict__ W = ph ? w1p : w1a;
        short v[8];
        #pragma unroll
        for (int j = 0; j < 8; ++j) {
            float x = W[(size_t)(k0 + j) * HHALF + col];
            _Float16 h = (_Float16)x;
            float r1 = x - (float)h;
            short lob = f32_to_bf16_bits(r1);
            float r2 = r1 - bf16_bits_to_f32(lob);
            v[j] = f32_to_bf16_bits(r2);
        }
        #pragma unroll
        for (int j = 0; j < 8; ++j) wt16[(size_t)WSL_BASE + (size_t)u2 * 8 + j] = v[j];
    }
}

// ---------------------------------------------------------------------------
// Main GEMM: 256 blocks (128 mblk x 2 ph), 512 thr (8 waves, 2M x 4N),
// wave tile 64x128. Single-accumulator 4-product split (scale 2048):
//   P1 f16(xh',wh) + P2 f16(xl',wh) + P3 bf16(xh_b,wlo_b) + P4 bf16(xh_b,wllo_b)
// B (wh+wlo) staged in LDS per K16-half via global_load_lds (dbuf), wllo from
// L2 regs, x from HBM staged to A-LDS (dbuf per K32). Counted vmcnt before
// each barrier (producer-side): even halves vmcnt(6), odd vmcnt(4).
// LDS 96KB: A dbuf [0,32K), B dbuf [32K,96K). Epilogue: H [0,32K), P [32K,64K).
// ---------------------------------------------------------------------------
__global__ void __launch_bounds__(512, 2)
qir_gemm(const float* __restrict__ xg, const _Float16* __restrict__ wt,
         const float* __restrict__ b1a, const float* __restrict__ w2a, const float* __restrict__ b2a,
         const float* __restrict__ b1p, const float* __restrict__ w2p, const float* __restrict__ b2p,
         float* __restrict__ out)
{
    extern __shared__ char smem[];
    const int tid = threadIdx.x;
    const int l  = tid & 63;
    const int w  = tid >> 6;
    const int wm = w >> 2;     // M half (0,1): rows wm*64..+63
    const int wn = w & 3;      // N quarter: cols wn*128..+127
    const int bid  = blockIdx.x;
    const int mblk = bid & 127;
    const int ph   = bid >> 7;
    const int tok0 = mblk * 128;

    const float* __restrict__ b1 = ph ? b1p : b1a;
    const float* __restrict__ w2 = ph ? w2p : w2a;
    const float* __restrict__ b2 = ph ? b2p : b2a;
    const _Float16* __restrict__ wsB = wt + (size_t)ph * WSB_PER_PH;
    const _Float16* __restrict__ wsL = wt + WSL_BASE + (size_t)ph * WSL_PER_PH;

    char* const Bb0 = smem + 32768;
    char* const Bb1 = smem + 65536;

    // A staging: thread -> (row r 0..127, k-quad kq 0..3); quads kq*4 and 16+kq*4
    const int r  = tid >> 2;
    const int kq = tid & 3;
    const float* __restrict__ aptr = xg + (size_t)(tok0 + r) * HDIM + kq * 4;
    // A tile layout: plane idx = (kh*2 + oct)*2 + pl, *2048; + row*16
    const int a_w  = (kq >> 1) * 4096 + r * 16 + (kq & 1) * 8;   // kh0; kh1 at +8192
    const int a_rd = (l >> 5) * 4096 + (wm * 64 + (l & 31)) * 16; // + kh*8192 + pl*2048 + m*512

    f32x16 acc[2][4];
    #pragma unroll
    for (int m = 0; m < 2; ++m)
        #pragma unroll
        for (int nf = 0; nf < 4; ++nf)
            #pragma unroll
            for (int rg = 0; rg < 16; ++rg) acc[m][nf][rg] = 0.0f;

    bf16x8 lloA[4], lloB[4];
    float4 xw0, xw1;

    auto stageA = [&](char* An, float4 v0, float4 v1) {
        half4 hv, lv;
        cvt_splitQ(v0, hv, lv);
        *(half4*)(An + a_w) = hv;
        *(half4*)(An + a_w + 2048) = lv;
        cvt_splitQ(v1, hv, lv);
        *(half4*)(An + 8192 + a_w) = hv;
        *(half4*)(An + 8192 + a_w + 2048) = lv;
    };
    auto gldsB = [&](int hkn, char* Bn) {
        const _Float16* src = wsB + (size_t)hkn * 16384 + (w * 4) * 512 + l * 8;
        char* dst = Bn + (w * 4) * 1024;
        #pragma unroll
        for (int q = 0; q < 4; ++q)
            __builtin_amdgcn_global_load_lds((gbl_void_t*)(src + q * 512),
                                             (lds_void_t*)(dst + q * 1024), 16, 0, 0);
    };
    auto loadLLO = [&](int hkn, bf16x8 (&d)[4]) {
        #pragma unroll
        for (int nf = 0; nf < 4; ++nf)
            d[nf] = *(const bf16x8*)(wsL + ((size_t)hkn * 16 + (wn * 4 + nf)) * 512 + l * 8);
    };

    // ---- prologue ----
    {
        float4 v0 = *(const float4*)(aptr);
        float4 v1 = *(const float4*)(aptr + 16);
        stageA(smem, v0, v1);
        gldsB(0, Bb0);
        loadLLO(0, lloA);
        __syncthreads();   // full drain before the counted-wait regime
    }

    auto halfStep = [&](int hk, int kh, char* Ac, char* An, char* Bc, char* Bn,
                        bf16x8 (&lc)[4], bf16x8 (&ln)[4], int p) {
        const bool even = (kh == 0);
        // issue prefetches in FIXED order (glds, llo, x) -- counts depend on it
        if (hk + 1 < 64) { gldsB(hk + 1, Bn); }
        SB();
        if (hk + 1 < 64) { loadLLO(hk + 1, ln); }
        SB();
        if (even && p + 1 < 32) {
            xw0 = *(const float4*)(aptr + (p + 1) * 32);
            xw1 = *(const float4*)(aptr + (p + 1) * 32 + 16);
        }
        SB();
        // A frags for this half
        const char* Abase = Ac + a_rd + kh * 8192;
        half8 xh0 = *(const half8*)(Abase);
        half8 xl0 = *(const half8*)(Abase + 2048);
        half8 xh1 = *(const half8*)(Abase + 512);
        half8 xl1 = *(const half8*)(Abase + 512 + 2048);
        bf16x8 xb0 = cvt_h2b(xh0);
        bf16x8 xb1 = cvt_h2b(xh1);
        #pragma unroll
        for (int nf = 0; nf < 4; ++nf) {
            const char* Bbase = Bc + ((wn * 4 + nf) * 2) * 1024 + l * 16;
            half8  wh  = *(const half8*)(Bbase);
            bf16x8 wlo = *(const bf16x8*)(Bbase + 1024);
            acc[0][nf] = MFMA_F16(xh0, wh, acc[0][nf]);
            acc[1][nf] = MFMA_F16(xh1, wh, acc[1][nf]);
            acc[0][nf] = MFMA_F16(xl0, wh, acc[0][nf]);
            acc[1][nf] = MFMA_F16(xl1, wh, acc[1][nf]);
            acc[0][nf] = MFMA_BF16(xb0, wlo, acc[0][nf]);
            acc[1][nf] = MFMA_BF16(xb1, wlo, acc[1][nf]);
            acc[0][nf] = MFMA_BF16(xb0, lc[nf], acc[0][nf]);
            acc[1][nf] = MFMA_BF16(xb1, lc[nf], acc[1][nf]);
        }
        if (!even && p + 1 < 32) stageA(An, xw0, xw1);
        // retire this half's glds before the barrier (leave llo [+x] in flight)
        if (even) asm volatile("s_waitcnt vmcnt(6)" ::: "memory");
        else      asm volatile("s_waitcnt vmcnt(4)" ::: "memory");
        BAR();
    };

    #pragma unroll 1
    for (int p = 0; p < 32; ++p) {
        char* Ac = smem + (p & 1) * 16384;
        char* An = smem + ((p + 1) & 1) * 16384;
        halfStep(2 * p,     0, Ac, An, Bb0, Bb1, lloA, lloB, p);
        halfStep(2 * p + 1, 1, Ac, An, Bb1, Bb0, lloB, lloA, p);
    }

    // ---- combine: h = gelu(acc/2048 + b1) ----
    float bcol[4];
    #pragma unroll
    for (int nf = 0; nf < 4; ++nf) bcol[nf] = b1[wn * 128 + nf * 32 + (l & 31)];
    #pragma unroll
    for (int m = 0; m < 2; ++m)
        #pragma unroll
        for (int nf = 0; nf < 4; ++nf)
            #pragma unroll
            for (int rg = 0; rg < 16; ++rg)
                acc[m][nf][rg] = gelu_exact(acc[m][nf][rg] * LO_SCALE_INV + bcol[nf]);

    // ---- fused GEMM2: wave contracts its 128 h-cols for its 64 rows ----
    char* const Hw = smem + w * 4096;            // wave-private [4 oct][64 rows][16B]
    char* const hb = Hw + ((l >> 3) & 3) * 1024 + (l & 7) * 2;
    float* const P = (float*)(smem + 32768);     // [8 waves][64 rows][16 e]

    f32x4 acc2[4], acc2s[4];
    #pragma unroll
    for (int m16 = 0; m16 < 4; ++m16)
        #pragma unroll
        for (int rg = 0; rg < 4; ++rg) { acc2[m16][rg] = 0.f; acc2s[m16][rg] = 0.f; }

#define H2PASS(ACC0, ACC1, NF, PL)                                             \
    {                                                                          \
        _Pragma("unroll")                                                      \
        for (int rg = 0; rg < 16; ++rg) {                                      \
            int row0 = (rg & 3) + 8 * (rg >> 2) + 4 * (l >> 5);                \
            { float vv = ACC0[rg]; _Float16 hh = (_Float16)vv;                 \
              *(_Float16*)(hb + row0 * 16) =                                   \
                  (PL) ? (_Float16)(vv - (float)hh) : hh; }                    \
            { float vv = ACC1[rg]; _Float16 hh = (_Float16)vv;                 \
              *(_Float16*)(hb + (32 + row0) * 16) =                            \
                  (PL) ? (_Float16)(vv - (float)hh) : hh; }                    \
        }                                                                      \
        _Pragma("unroll")                                                      \
        for (int m16 = 0; m16 < 4; ++m16) {                                    \
            half8 a2 = *(const half8*)(Hw + (l >> 4) * 1024 +                  \
                                       (m16 * 16 + (l & 15)) * 16);            \
            acc2[m16] = MFMA16(a2, w2h[NF], acc2[m16]);                        \
            if (!(PL)) acc2s[m16] = MFMA16(a2, w2l[NF], acc2s[m16]);           \
        }                                                                      \
    }

    #pragma unroll
    for (int ch = 0; ch < 2; ++ch) {
        half8 w2h[2], w2l[2];
        #pragma unroll
        for (int nf2 = 0; nf2 < 2; ++nf2) {
            #pragma unroll
            for (int j = 0; j < 8; ++j) {
                int kg = wn * 128 + ch * 64 + nf2 * 32 + (l >> 4) * 8 + j;
                float vv = w2[(size_t)kg * NE + (l & 15)];
                _Float16 hh = (_Float16)vv;
                w2h[nf2][j] = hh;
                w2l[nf2][j] = (_Float16)((vv - (float)hh) * LO_SCALE);
            }
        }
        H2PASS(acc[0][ch * 2 + 0], acc[1][ch * 2 + 0], 0, 0)
        H2PASS(acc[0][ch * 2 + 1], acc[1][ch * 2 + 1], 1, 0)
        H2PASS(acc[0][ch * 2 + 0], acc[1][ch * 2 + 0], 0, 1)
        H2PASS(acc[0][ch * 2 + 1], acc[1][ch * 2 + 1], 1, 1)
    }
#undef H2PASS

    #pragma unroll
    for (int m16 = 0; m16 < 4; ++m16)
        #pragma unroll
        for (int rg = 0; rg < 4; ++rg) {
            int row = m16 * 16 + ((l >> 4) << 2) + rg;
            P[w * 1024 + row * 16 + (l & 15)] =
                acc2[m16][rg] + acc2s[m16][rg] * LO_SCALE_INV;
        }
    __syncthreads();

    // final reduce over the 4 N-waves of each M-half; single writer, no atomics
    #pragma unroll
    for (int rep = 0; rep < 4; ++rep) {
        int oi = tid + rep * 512;
        int t = oi >> 4, e = oi & 15;
        int mh = t >> 6, tl = t & 63;
        float sum = b2[e]
                  + P[(mh * 4 + 0) * 1024 + tl * 16 + e]
                  + P[(mh * 4 + 1) * 1024 + tl * 16 + e]
                  + P[(mh * 4 + 2) * 1024 + tl * 16 + e]
                  + P[(mh * 4 + 3) * 1024 + tl * 16 + e];
        out[(ph ? OFF_PH : OFF_PR) + (size_t)(tok0 + t) * NE + e] = sum;
    }
}

// ---------------------------------------------------------------------------
// Fallback (R1 kernel, raw-output variant) if ws too small for the images.
// ---------------------------------------------------------------------------
__global__ void __launch_bounds__(512)
qir_mlp(const float* __restrict__ xg,
        const float* __restrict__ w1a, const float* __restrict__ b1a,
        const float* __restrict__ w2a, const float* __restrict__ b2a,
        const float* __restrict__ w1p, const float* __restrict__ b1p,
        const float* __restrict__ w2p, const float* __restrict__ b2p,
        float* __restrict__ out)
{
    __shared__ float sh_w[16][HHALF];
    __shared__ float sh_x[16][68];

    const int tid  = threadIdx.x;
    const int cg   = tid & 63;
    const int tg   = tid >> 6;
    const int tok0 = blockIdx.x * 64;
    const int cA   = cg * 4;
    const int cB   = 256 + cg * 4;

    for (int phase = 0; phase < 2; ++phase) {
        const float* __restrict__ w1 = phase ? w1p : w1a;
        const float* __restrict__ b1 = phase ? b1p : b1a;
        const float* __restrict__ w2 = phase ? w2p : w2a;
        const float* __restrict__ b2 = phase ? b2p : b2a;

        float acc[8][8];
        #pragma unroll
        for (int t = 0; t < 8; ++t)
            #pragma unroll
            for (int c = 0; c < 8; ++c) acc[t][c] = 0.0f;

        float4 wreg[4];
        float4 xreg = make_float4(0.f, 0.f, 0.f, 0.f);

        auto load_chunk = [&](int kc) {
            #pragma unroll
            for (int p = 0; p < 4; ++p) {
                int f  = tid + p * 512;
                int k  = f >> 7;
                int c4 = (f & 127) << 2;
                wreg[p] = *(const float4*)&w1[(kc * 16 + k) * HHALF + c4];
            }
            if (tid < 256) {
                int t  = tid >> 2;
                int k4 = (tid & 3) << 2;
                xreg = *(const float4*)&xg[(size_t)(tok0 + t) * HDIM + kc * 16 + k4];
            }
        };

        load_chunk(0);
        for (int kc = 0; kc < HDIM / 16; ++kc) {
            __syncthreads();
            #pragma unroll
            for (int p = 0; p < 4; ++p) {
                int f  = tid + p * 512;
                int k  = f >> 7;
                int c4 = (f & 127) << 2;
                *(float4*)&sh_w[k][c4] = wreg[p];
            }
            if (tid < 256) {
                int t  = tid >> 2;
                int k4 = (tid & 3) << 2;
                sh_x[k4 + 0][t] = xreg.x;
                sh_x[k4 + 1][t] = xreg.y;
                sh_x[k4 + 2][t] = xreg.z;
                sh_x[k4 + 3][t] = xreg.w;
            }
            __syncthreads();
            if (kc + 1 < HDIM / 16) load_chunk(kc + 1);

            #pragma unroll 4
            for (int k = 0; k < 16; ++k) {
                float4 xa = *(const float4*)&sh_x[k][tg * 8];
                float4 xb = *(const float4*)&sh_x[k][tg * 8 + 4];
                float4 wa = *(const float4*)&sh_w[k][cA];
                float4 wb = *(const float4*)&sh_w[k][cB];
                float xs[8] = {xa.x, xa.y, xa.z, xa.w, xb.x, xb.y, xb.z, xb.w};
                float ws[8] = {wa.x, wa.y, wa.z, wa.w, wb.x, wb.y, wb.z, wb.w};
                #pragma unroll
                for (int t = 0; t < 8; ++t)
                    #pragma unroll
                    for (int c = 0; c < 8; ++c)
                        acc[t][c] = fmaf(xs[t], ws[c], acc[t][c]);
            }
        }

        {
            float4 bA4 = *(const float4*)&b1[cA];
            float4 bB4 = *(const float4*)&b1[cB];
            float bs[8] = {bA4.x, bA4.y, bA4.z, bA4.w, bB4.x, bB4.y, bB4.z, bB4.w};
            #pragma unroll
            for (int t = 0; t < 8; ++t)
                #pragma unroll
                for (int c = 0; c < 8; ++c)
                    acc[t][c] = gelu_exact(acc[t][c] + bs[c]);
        }

        for (int e = 0; e < NE; ++e) {
            float w2v[8];
            #pragma unroll
            for (int j = 0; j < 4; ++j) {
                w2v[j]     = w2[(cA + j) * NE + e];
                w2v[4 + j] = w2[(cB + j) * NE + e];
            }
            float bias2 = b2[e];
            #pragma unroll
            for (int t = 0; t < 8; ++t) {
                float s = 0.0f;
                #pragma unroll
                for (int j = 0; j < 8; ++j) s = fmaf(acc[t][j], w2v[j], s);
                #pragma unroll
                for (int off = 1; off < 64; off <<= 1)
                    s += __shfl_xor(s, off, 64);
                if (cg == 0) {
                    float raw   = s + bias2;
                    int   token = tok0 + tg * 8 + t;
                    out[(phase ? OFF_PH : OFF_PR) + (size_t)token * NE + e] = raw;
                }
            }
        }
    }
}

// ---------------------------------------------------------------------------
// Per-token epilogue: tanh on raw phases; softmax/rotations/probs/top-2.
// ---------------------------------------------------------------------------
__global__ void __launch_bounds__(256)
qir_epilogue(const float* __restrict__ ent, float* __restrict__ out)
{
    __shared__ float sh_c[120], sh_s[120];
    const int tid = threadIdx.x;
    if (tid < 120) {
        int rem = tid, i = 0;
        while (rem >= 15 - i) { rem -= 15 - i; ++i; }
        int j = i + 1 + rem;
        float ang = ent[i * NE + j] * 0.5f;
        sh_c[tid] = cosf(ang);
        sh_s[tid] = sinf(ang);
    }
    __syncthreads();

    const int token = blockIdx.x * 256 + tid;

    #pragma unroll
    for (int q = 0; q < 4; ++q) {
        float4 v = *(const float4*)&out[OFF_PH + (size_t)token * NE + q * 4];
        v.x = tanhf(v.x) * 3.14159265358979323846f;
        v.y = tanhf(v.y) * 3.14159265358979323846f;
        v.z = tanhf(v.z) * 3.14159265358979323846f;
        v.w = tanhf(v.w) * 3.14159265358979323846f;
        *(float4*)&out[OFF_PH + (size_t)token * NE + q * 4] = v;
    }

    float a[16];
    #pragma unroll
    for (int q = 0; q < 4; ++q) {
        float4 v = *(const float4*)&out[OFF_PR + (size_t)token * NE + q * 4];
        a[q*4+0] = v.x; a[q*4+1] = v.y; a[q*4+2] = v.z; a[q*4+3] = v.w;
    }

    float m = fabsf(a[0]);
    #pragma unroll
    for (int e = 1; e < 16; ++e) m = fmaxf(m, fabsf(a[e]));
    float ssum = 0.0f;
    #pragma unroll
    for (int e = 0; e < 16; ++e) { a[e] = expf(fabsf(a[e]) - m); ssum += a[e]; }
    float inv = 1.0f / ssum;
    #pragma unroll
    for (int e = 0; e < 16; ++e) a[e] = sqrtf(a[e] * inv);

    {
        int p = 0;
        #pragma unroll
        for (int i = 0; i < 16; ++i) {
            #pragma unroll
            for (int j = i + 1; j < 16; ++j) {
                float c = sh_c[p], s = sh_s[p]; ++p;
                float ai = a[i], aj = a[j];
                a[i] = c * ai - s * aj;
                a[j] = s * ai + c * aj;
            }
        }
    }

    #pragma unroll
    for (int q = 0; q < 4; ++q)
        *(float4*)&out[OFF_DEC + (size_t)token * NE + q * 4] =
            make_float4(a[q*4], a[q*4+1], a[q*4+2], a[q*4+3]);

    float pr[16];
    float s2 = 0.0f;
    #pragma unroll
    for (int e = 0; e < 16; ++e) { pr[e] = a[e] * a[e]; s2 += pr[e]; }
    float inv2 = 1.0f / fmaxf(s2, 1e-12f);
    #pragma unroll
    for (int e = 0; e < 16; ++e) pr[e] *= inv2;
    #pragma unroll
    for (int q = 0; q < 4; ++q)
        *(float4*)&out[OFF_PR + (size_t)token * NE + q * 4] =
            make_float4(pr[q*4], pr[q*4+1], pr[q*4+2], pr[q*4+3]);

    float bv = pr[0]; int bi = 0;
    #pragma unroll
    for (int e = 1; e < 16; ++e) if (pr[e] > bv) { bv = pr[e]; bi = e; }
    float sv = -1.0f; int si = 0;
    #pragma unroll
    for (int e = 0; e < 16; ++e) if (e != bi && pr[e] > sv) { sv = pr[e]; si = e; }
    float ts = fmaxf(fabsf(bv) + fabsf(sv), 1e-12f);
    out[OFF_TP + (size_t)token * 2 + 0] = bv / ts;
    out[OFF_TP + (size_t)token * 2 + 1] = sv / ts;
    out[OFF_TI + (size_t)token * 2 + 0] = (float)bi;
    out[OFF_TI + (size_t)token * 2 + 1] = (float)si;
}

extern "C" void kernel_launch(void* const* d_in, const int* in_sizes, int n_in,
                              void* d_out, int out_size, void* d_ws, size_t ws_size,
                              hipStream_t stream) {
    const float* xg  = (const float*)d_in[0];
    const float* w1a = (const float*)d_in[1];
    const float* b1a = (const float*)d_in[2];
    const float* w2a = (const float*)d_in[3];
    const float* b2a = (const float*)d_in[4];
    const float* w1p = (const float*)d_in[5];
    const float* b1p = (const float*)d_in[6];
    const float* w2p = (const float*)d_in[7];
    const float* b2p = (const float*)d_in[8];
    const float* ent = (const float*)d_in[9];
    float* out = (float*)d_out;

    if (ws_size >= WS_BYTES) {
        _Float16* wt = (_Float16*)d_ws;
        qir_wtrans<<<1536, 256, 0, stream>>>(w1a, w1p, wt);
        qir_gemm<<<256, 512, 98304, stream>>>(xg, wt, b1a, w2a, b2a,
                                              b1p, w2p, b2p, out);
    } else {
        qir_mlp<<<NTOK / 64, 512, 0, stream>>>(xg, w1a, b1a, w2a, b2a,
                                               w1p, b1p, w2p, b2p, out);
    }
    qir_epilogue<<<NTOK / 256, 256, 0, stream>>>(ent, out);
}

// Round 10
// 132.086 us; speedup vs baseline: 1.9389x; 1.9389x over previous
//
#include <hip/hip_runtime.h>
#include <math.h>

#define NTOK   16384
#define HDIM   1024
#define HHALF  512
#define NE     16

// d_out layout (concatenated reference outputs, all f32; indices stored as float)
#define OFF_TP  0
#define OFF_TI  (NTOK * 2)
#define OFF_DEC (NTOK * 4)
#define OFF_PH  (OFF_DEC + NTOK * NE)
#define OFF_PR  (OFF_PH + NTOK * NE)

typedef _Float16 half8 __attribute__((ext_vector_type(8)));
typedef _Float16 half4 __attribute__((ext_vector_type(4)));
typedef float f32x16 __attribute__((ext_vector_type(16)));
typedef float f32x4 __attribute__((ext_vector_type(4)));

#define LO_SCALE     2048.0f
#define LO_SCALE_INV (1.0f / 2048.0f)
#define MFMA32(a,b,c) __builtin_amdgcn_mfma_f32_32x32x16_f16(a,b,c,0,0,0)
#define MFMA16(a,b,c) __builtin_amdgcn_mfma_f32_16x16x32_f16(a,b,c,0,0,0)

// Raw barrier: lgkmcnt(0) gives LDS write-visibility + read completion before
// the barrier; vmcnt is NOT drained (global prefetches stay in flight).
#define BAR() asm volatile("s_waitcnt lgkmcnt(0)\n\ts_barrier" ::: "memory")
#define LGKM0_FENCE() do {                                        \
    asm volatile("s_waitcnt lgkmcnt(0)" ::: "memory");            \
    __builtin_amdgcn_sched_barrier(0);                            \
} while (0)

__device__ __forceinline__ float gelu_exact(float x) {
    return 0.5f * x * (1.0f + erff(x * 0.70710678118654752440f));
}

__device__ __forceinline__ void cvt_split(float4 v, half4& hi, half4& lo) {
    _Float16 h0 = (_Float16)v.x, h1 = (_Float16)v.y,
             h2 = (_Float16)v.z, h3 = (_Float16)v.w;
    hi = (half4){h0, h1, h2, h3};
    lo = (half4){(_Float16)((v.x - (float)h0) * LO_SCALE),
                 (_Float16)((v.y - (float)h1) * LO_SCALE),
                 (_Float16)((v.z - (float)h2) * LO_SCALE),
                 (_Float16)((v.w - (float)h3) * LO_SCALE)};
}

// ---------------------------------------------------------------------------
// Prologue: build register-fragment B image in ws AND zero the PH/PR raw-sum
// accumulation regions of d_out (gemm blocks atomicAdd into them).
// Image (f16 elems): addr16 = 8*u where u = ((((ph*32+kc)*8+sl)*8+f)*64+l);
// f = nf*4 + kh*2 + pl. Value: col = sl*64+nf*32+(l&31),
// k = kc*32+kh*16+(l>>5)*8+j; pl=0 -> f16(W[k][col]), pl=1 -> (W-hi)*2048.
// ---------------------------------------------------------------------------
__global__ void __launch_bounds__(256)
qir_wtrans(const float* __restrict__ w1a, const float* __restrict__ w1p,
           _Float16* __restrict__ wt, float* __restrict__ out)
{
    int u = blockIdx.x * 256 + threadIdx.x;   // 0..262143
    out[OFF_PH + u] = 0.0f;
    out[OFF_PH + 262144 + u] = 0.0f;

    int l  = u & 63;
    int f  = (u >> 6) & 7;
    int sl = (u >> 9) & 7;
    int kc = (u >> 12) & 31;
    int ph = u >> 17;
    int nf = f >> 2, kh = (f >> 1) & 1, pl = f & 1;
    int col = sl * 64 + nf * 32 + (l & 31);
    int k0  = kc * 32 + kh * 16 + (l >> 5) * 8;
    const float* __restrict__ W = ph ? w1p : w1a;
    half8 v;
    #pragma unroll
    for (int j = 0; j < 8; ++j) {
        float x = W[(size_t)(k0 + j) * HHALF + col];
        _Float16 h = (_Float16)x;
        v[j] = pl ? (_Float16)((x - (float)h) * LO_SCALE) : h;
    }
    *(half8*)&wt[(size_t)u * 8] = v;
}

// ---------------------------------------------------------------------------
// Main GEMM: block = 64 tokens x 256 cols x one phase; 4 waves, wave tile
// 64x64 (R8 geometry). Two blocks co-reside per CU (independent barrier
// domains). K-step split into TWO barrier-isolated phases (m201/T3 pattern):
// each phase = {issue half the prefetch, ds_read 4 A frags, lgkm0 fence,
// setprio(1) 12-MFMA cluster setprio(0), barrier}. vmcnt never drained in
// the loop; counted waits appear at the prefetch consumers (T4).
// A buf layout: hi = kh*2048 + oct2*1024 + row*16, lo at +4096.
// ---------------------------------------------------------------------------
__device__ __forceinline__ void kstep(
    int kc, const float* __restrict__ aptr, const _Float16* __restrict__ bptr,
    char* Acur, char* Anxt, int a_rd, int a_off0, int a_off1,
    half8 (&Bc)[8], half8 (&Bn)[8],
    float4 (&xw)[2], float4 (&xl)[2],
    f32x16& a00, f32x16& a01, f32x16& a10, f32x16& a11,
    f32x16& c00, f32x16& c01, f32x16& c10, f32x16& c11)
{
    // ================= phase A (kh = 0) =================
    // issue next-next x and first half of next B frags (in flight across both barriers)
    if (kc + 2 < 32) {
        xl[0] = *(const float4*)(aptr + (kc + 2) * 32);
        xl[1] = *(const float4*)(aptr + (kc + 2) * 32 + 16);
    }
    if (kc + 1 < 32) {
        #pragma unroll
        for (int f = 0; f < 4; ++f)
            Bn[f] = *(const half8*)(bptr + (size_t)(kc + 1) * 32768 + f * 512);
    }
    {
        const char* Ah = Acur + a_rd;                 // kh = 0
        half8 ah0 = *(const half8*)(Ah);
        half8 ah1 = *(const half8*)(Ah + 512);
        half8 al0 = *(const half8*)(Ah + 4096);
        half8 al1 = *(const half8*)(Ah + 4096 + 512);
        LGKM0_FENCE();
        __builtin_amdgcn_s_setprio(1);
        {
            half8 bh0 = Bc[0], bl0 = Bc[1], bh1 = Bc[4], bl1 = Bc[5];
            a00 = MFMA32(ah0, bh0, a00); c00 = MFMA32(al0, bh0, c00); c00 = MFMA32(ah0, bl0, c00);
            a01 = MFMA32(ah0, bh1, a01); c01 = MFMA32(al0, bh1, c01); c01 = MFMA32(ah0, bl1, c01);
            a10 = MFMA32(ah1, bh0, a10); c10 = MFMA32(al1, bh0, c10); c10 = MFMA32(ah1, bl0, c10);
            a11 = MFMA32(ah1, bh1, a11); c11 = MFMA32(al1, bh1, c11); c11 = MFMA32(ah1, bl1, c11);
        }
        __builtin_amdgcn_s_setprio(0);
    }
    __builtin_amdgcn_s_barrier();   // no LDS writes this phase: raw barrier

    // ================= phase B (kh = 1) =================
    if (kc + 1 < 32) {
        #pragma unroll
        for (int f = 4; f < 8; ++f)
            Bn[f] = *(const half8*)(bptr + (size_t)(kc + 1) * 32768 + f * 512);
    }
    {
        const char* Ah = Acur + 2048 + a_rd;          // kh = 1
        half8 ah0 = *(const half8*)(Ah);
        half8 ah1 = *(const half8*)(Ah + 512);
        half8 al0 = *(const half8*)(Ah + 4096);
        half8 al1 = *(const half8*)(Ah + 4096 + 512);
        LGKM0_FENCE();
        __builtin_amdgcn_s_setprio(1);
        {
            half8 bh0 = Bc[2], bl0 = Bc[3], bh1 = Bc[6], bl1 = Bc[7];
            a00 = MFMA32(ah0, bh0, a00); c00 = MFMA32(al0, bh0, c00); c00 = MFMA32(ah0, bl0, c00);
            a01 = MFMA32(ah0, bh1, a01); c01 = MFMA32(al0, bh1, c01); c01 = MFMA32(ah0, bl1, c01);
            a10 = MFMA32(ah1, bh0, a10); c10 = MFMA32(al1, bh0, c10); c10 = MFMA32(ah1, bl0, c10);
            a11 = MFMA32(ah1, bh1, a11); c11 = MFMA32(al1, bh1, c11); c11 = MFMA32(ah1, bl1, c11);
        }
        __builtin_amdgcn_s_setprio(0);
    }
    if (kc + 1 < 32) {
        half4 hv, lv;
        cvt_split(xw[0], hv, lv);
        *(half4*)(Anxt + a_off0) = hv; *(half4*)(Anxt + a_off0 + 4096) = lv;
        cvt_split(xw[1], hv, lv);
        *(half4*)(Anxt + a_off1) = hv; *(half4*)(Anxt + a_off1 + 4096) = lv;
    }
    BAR();
}

__global__ void __launch_bounds__(256, 2)
qir_gemm(const float* __restrict__ xg, const _Float16* __restrict__ wt,
         const float* __restrict__ b1a, const float* __restrict__ w2a, const float* __restrict__ b2a,
         const float* __restrict__ b1p, const float* __restrict__ w2p, const float* __restrict__ b2p,
         float* __restrict__ out)
{
    extern __shared__ char smem[];   // 32KB: A dbuf [0,8K)+[8K,16K);
                                     // epilogue: H [0,16K), P [16K,32K)
    const int tid = threadIdx.x;
    const int l  = tid & 63;
    const int w  = tid >> 6;   // wave 0..3 owns col slice w*64..w*64+63
    // XCD-aligned decode: the 4 blocks sharing an x-panel (2ph x 2nh) have
    // bids m, m+256, m+512, m+768 -> all == m (mod 8) -> same XCD L2.
    // Consecutive bids (same v) share the ENTIRE B panel -> co-resident
    // blocks on a CU serve B from L1/L2.
    const int bid  = blockIdx.x;
    const int mblk = bid & 255;
    const int v    = bid >> 8;
    const int ph   = v & 1;
    const int nh   = v >> 1;
    const int tok0 = mblk * 64;

    const float* __restrict__ b1 = ph ? b1p : b1a;
    const float* __restrict__ w2 = ph ? w2p : w2a;
    const float* __restrict__ b2 = ph ? b2p : b2a;
    const _Float16* __restrict__ wtp = wt + ((size_t)ph << 20);

    char* const Ab0 = smem;
    char* const Ab1 = smem + 8192;

    // A staging: thread -> (row r 0..63, k-quads kq and kq+4)
    const int r  = tid >> 2;
    const int kq = tid & 3;
    const float* __restrict__ aptr = xg + (size_t)(tok0 + r) * HDIM + kq * 4;
    const int a_off0 = (kq >> 1) * 1024 + r * 16 + (kq & 1) * 8;   // kh=0
    const int a_off1 = a_off0 + 2048;                               // kh=1
    // A frag read: oct2 (l>>5), row (l&31)
    const int a_rd = (l >> 5) * 1024 + (l & 31) * 16;

    // B frag pointer (f16 units): slice sl = nh*4 + w
    const _Float16* __restrict__ bptr = wtp + (nh * 4 + w) * 4096 + (size_t)l * 8;

    f32x16 a00{}, a01{}, a10{}, a11{}, c00{}, c01{}, c10{}, c11{};
    #pragma unroll
    for (int rg = 0; rg < 16; ++rg) {
        a00[rg] = 0.f; a01[rg] = 0.f; a10[rg] = 0.f; a11[rg] = 0.f;
        c00[rg] = 0.f; c01[rg] = 0.f; c10[rg] = 0.f; c11[rg] = 0.f;
    }

    half8 Bc[8], Bn[8];
    float4 xw[2], xl[2];

    // prologue: stage A(0), preload B(0), prefetch x(1)
    {
        float4 v0 = *(const float4*)(aptr);
        float4 v1 = *(const float4*)(aptr + 16);
        half4 hv, lv;
        cvt_split(v0, hv, lv);
        *(half4*)(Ab0 + a_off0) = hv; *(half4*)(Ab0 + a_off0 + 4096) = lv;
        cvt_split(v1, hv, lv);
        *(half4*)(Ab0 + a_off1) = hv; *(half4*)(Ab0 + a_off1 + 4096) = lv;
    }
    #pragma unroll
    for (int f = 0; f < 8; ++f) Bc[f] = *(const half8*)(bptr + f * 512);
    xw[0] = *(const float4*)(aptr + 32);
    xw[1] = *(const float4*)(aptr + 48);
    BAR();

    for (int kk = 0; kk < 16; ++kk) {
        kstep(2 * kk,     aptr, bptr, Ab0, Ab1, a_rd, a_off0, a_off1,
              Bc, Bn, xw, xl, a00, a01, a10, a11, c00, c01, c10, c11);
        kstep(2 * kk + 1, aptr, bptr, Ab1, Ab0, a_rd, a_off0, a_off1,
              Bn, Bc, xl, xw, a00, a01, a10, a11, c00, c01, c10, c11);
    }

    // combine split accumulators + bias + exact gelu (h values kept in acc)
    const int col0 = nh * 256 + w * 64 + (l & 31);
    const float bb0 = b1[col0], bb1 = b1[col0 + 32];
    #pragma unroll
    for (int rg = 0; rg < 16; ++rg) {
        a00[rg] = gelu_exact(a00[rg] + c00[rg] * LO_SCALE_INV + bb0);
        a01[rg] = gelu_exact(a01[rg] + c01[rg] * LO_SCALE_INV + bb1);
        a10[rg] = gelu_exact(a10[rg] + c10[rg] * LO_SCALE_INV + bb0);
        a11[rg] = gelu_exact(a11[rg] + c11[rg] * LO_SCALE_INV + bb1);
    }

    // ---- fused partial GEMM2 over this block's 256 h-cols (R5 layout) ----
    char* const Hw = smem + w * 4096;            // wave-private [4 oct][64 rows][16B]
    char* const hb = Hw + ((l >> 3) & 3) * 1024 + (l & 7) * 2;
    float* const P = (float*)(smem + 16384);     // [4 waves][64 tok][16 e]

    half8 w2h[2], w2l[2];
    #pragma unroll
    for (int nf = 0; nf < 2; ++nf) {
        #pragma unroll
        for (int j = 0; j < 8; ++j) {
            int kg = nh * 256 + w * 64 + nf * 32 + (l >> 4) * 8 + j;
            float vv = w2[(size_t)kg * NE + (l & 15)];
            _Float16 hh = (_Float16)vv;
            w2h[nf][j] = hh;
            w2l[nf][j] = (_Float16)((vv - (float)hh) * LO_SCALE);
        }
    }

    f32x4 acc2[4], acc2s[4];
    #pragma unroll
    for (int m16 = 0; m16 < 4; ++m16)
        #pragma unroll
        for (int rg = 0; rg < 4; ++rg) { acc2[m16][rg] = 0.f; acc2s[m16][rg] = 0.f; }

#define H2PASS(ACC0, ACC1, NF, PL)                                             \
    {                                                                          \
        _Pragma("unroll")                                                      \
        for (int rg = 0; rg < 16; ++rg) {                                      \
            int row0 = (rg & 3) + 8 * (rg >> 2) + 4 * (l >> 5);                \
            { float vv = ACC0[rg]; _Float16 hh = (_Float16)vv;                 \
              *(_Float16*)(hb + row0 * 16) =                                   \
                  (PL) ? (_Float16)(vv - (float)hh) : hh; }                    \
            { float vv = ACC1[rg]; _Float16 hh = (_Float16)vv;                 \
              *(_Float16*)(hb + (32 + row0) * 16) =                            \
                  (PL) ? (_Float16)(vv - (float)hh) : hh; }                    \
        }                                                                      \
        _Pragma("unroll")                                                      \
        for (int m16 = 0; m16 < 4; ++m16) {                                    \
            half8 a2 = *(const half8*)(Hw + (l >> 4) * 1024 +                  \
                                       (m16 * 16 + (l & 15)) * 16);            \
            acc2[m16] = MFMA16(a2, w2h[NF], acc2[m16]);                        \
            if (!(PL)) acc2s[m16] = MFMA16(a2, w2l[NF], acc2s[m16]);           \
        }                                                                      \
    }

    H2PASS(a00, a10, 0, 0)
    H2PASS(a01, a11, 1, 0)
    H2PASS(a00, a10, 0, 1)
    H2PASS(a01, a11, 1, 1)
#undef H2PASS

    #pragma unroll
    for (int m16 = 0; m16 < 4; ++m16)
        #pragma unroll
        for (int rg = 0; rg < 4; ++rg) {
            int row = m16 * 16 + ((l >> 4) << 2) + rg;
            P[w * 1024 + row * 16 + (l & 15)] =
                acc2[m16][rg] + acc2s[m16][rg] * LO_SCALE_INV;
        }
    __syncthreads();

    #pragma unroll
    for (int rep = 0; rep < 4; ++rep) {
        int oi = tid + rep * 256;
        int t = oi >> 4, e = oi & 15;
        float sum = 0.5f * b2[e]
                  + P[0 * 1024 + t * 16 + e]
                  + P[1 * 1024 + t * 16 + e]
                  + P[2 * 1024 + t * 16 + e]
                  + P[3 * 1024 + t * 16 + e];
        atomicAdd(out + (ph ? OFF_PH : OFF_PR) + (size_t)(tok0 + t) * NE + e, sum);
    }
}

// ---------------------------------------------------------------------------
// Fallback (R1 kernel, raw-phase variant) if ws too small for the WT image.
// ---------------------------------------------------------------------------
__global__ void __launch_bounds__(512)
qir_mlp(const float* __restrict__ xg,
        const float* __restrict__ w1a, const float* __restrict__ b1a,
        const float* __restrict__ w2a, const float* __restrict__ b2a,
        const float* __restrict__ w1p, const float* __restrict__ b1p,
        const float* __restrict__ w2p, const float* __restrict__ b2p,
        float* __restrict__ out)
{
    __shared__ float sh_w[16][HHALF];
    __shared__ float sh_x[16][68];

    const int tid  = threadIdx.x;
    const int cg   = tid & 63;
    const int tg   = tid >> 6;
    const int tok0 = blockIdx.x * 64;
    const int cA   = cg * 4;
    const int cB   = 256 + cg * 4;

    for (int phase = 0; phase < 2; ++phase) {
        const float* __restrict__ w1 = phase ? w1p : w1a;
        const float* __restrict__ b1 = phase ? b1p : b1a;
        const float* __restrict__ w2 = phase ? w2p : w2a;
        const float* __restrict__ b2 = phase ? b2p : b2a;

        float acc[8][8];
        #pragma unroll
        for (int t = 0; t < 8; ++t)
            #pragma unroll
            for (int c = 0; c < 8; ++c) acc[t][c] = 0.0f;

        float4 wreg[4];
        float4 xreg = make_float4(0.f, 0.f, 0.f, 0.f);

        auto load_chunk = [&](int kc) {
            #pragma unroll
            for (int p = 0; p < 4; ++p) {
                int f  = tid + p * 512;
                int k  = f >> 7;
                int c4 = (f & 127) << 2;
                wreg[p] = *(const float4*)&w1[(kc * 16 + k) * HHALF + c4];
            }
            if (tid < 256) {
                int t  = tid >> 2;
                int k4 = (tid & 3) << 2;
                xreg = *(const float4*)&xg[(size_t)(tok0 + t) * HDIM + kc * 16 + k4];
            }
        };

        load_chunk(0);
        for (int kc = 0; kc < HDIM / 16; ++kc) {
            __syncthreads();
            #pragma unroll
            for (int p = 0; p < 4; ++p) {
                int f  = tid + p * 512;
                int k  = f >> 7;
                int c4 = (f & 127) << 2;
                *(float4*)&sh_w[k][c4] = wreg[p];
            }
            if (tid < 256) {
                int t  = tid >> 2;
                int k4 = (tid & 3) << 2;
                sh_x[k4 + 0][t] = xreg.x;
                sh_x[k4 + 1][t] = xreg.y;
                sh_x[k4 + 2][t] = xreg.z;
                sh_x[k4 + 3][t] = xreg.w;
            }
            __syncthreads();
            if (kc + 1 < HDIM / 16) load_chunk(kc + 1);

            #pragma unroll 4
            for (int k = 0; k < 16; ++k) {
                float4 xa = *(const float4*)&sh_x[k][tg * 8];
                float4 xb = *(const float4*)&sh_x[k][tg * 8 + 4];
                float4 wa = *(const float4*)&sh_w[k][cA];
                float4 wb = *(const float4*)&sh_w[k][cB];
                float xs[8] = {xa.x, xa.y, xa.z, xa.w, xb.x, xb.y, xb.z, xb.w};
                float ws[8] = {wa.x, wa.y, wa.z, wa.w, wb.x, wb.y, wb.z, wb.w};
                #pragma unroll
                for (int t = 0; t < 8; ++t)
                    #pragma unroll
                    for (int c = 0; c < 8; ++c)
                        acc[t][c] = fmaf(xs[t], ws[c], acc[t][c]);
            }
        }

        {
            float4 bA4 = *(const float4*)&b1[cA];
            float4 bB4 = *(const float4*)&b1[cB];
            float bs[8] = {bA4.x, bA4.y, bA4.z, bA4.w, bB4.x, bB4.y, bB4.z, bB4.w};
            #pragma unroll
            for (int t = 0; t < 8; ++t)
                #pragma unroll
                for (int c = 0; c < 8; ++c)
                    acc[t][c] = gelu_exact(acc[t][c] + bs[c]);
        }

        for (int e = 0; e < NE; ++e) {
            float w2v[8];
            #pragma unroll
            for (int j = 0; j < 4; ++j) {
                w2v[j]     = w2[(cA + j) * NE + e];
                w2v[4 + j] = w2[(cB + j) * NE + e];
            }
            float bias2 = b2[e];
            #pragma unroll
            for (int t = 0; t < 8; ++t) {
                float s = 0.0f;
                #pragma unroll
                for (int j = 0; j < 8; ++j) s = fmaf(acc[t][j], w2v[j], s);
                #pragma unroll
                for (int off = 1; off < 64; off <<= 1)
                    s += __shfl_xor(s, off, 64);
                if (cg == 0) {
                    float raw   = s + bias2;
                    int   token = tok0 + tg * 8 + t;
                    out[(phase ? OFF_PH : OFF_PR) + (size_t)token * NE + e] = raw;
                }
            }
        }
    }
}

// ---------------------------------------------------------------------------
// Per-token epilogue: tanh on raw phases; softmax/rotations/probs/top-2.
// ---------------------------------------------------------------------------
__global__ void __launch_bounds__(256)
qir_epilogue(const float* __restrict__ ent, float* __restrict__ out)
{
    __shared__ float sh_c[120], sh_s[120];
    const int tid = threadIdx.x;
    if (tid < 120) {
        int rem = tid, i = 0;
        while (rem >= 15 - i) { rem -= 15 - i; ++i; }
        int j = i + 1 + rem;
        float ang = ent[i * NE + j] * 0.5f;
        sh_c[tid] = cosf(ang);
        sh_s[tid] = sinf(ang);
    }
    __syncthreads();

    const int token = blockIdx.x * 256 + tid;

    #pragma unroll
    for (int q = 0; q < 4; ++q) {
        float4 v = *(const float4*)&out[OFF_PH + (size_t)token * NE + q * 4];
        v.x = tanhf(v.x) * 3.14159265358979323846f;
        v.y = tanhf(v.y) * 3.14159265358979323846f;
        v.z = tanhf(v.z) * 3.14159265358979323846f;
        v.w = tanhf(v.w) * 3.14159265358979323846f;
        *(float4*)&out[OFF_PH + (size_t)token * NE + q * 4] = v;
    }

    float a[16];
    #pragma unroll
    for (int q = 0; q < 4; ++q) {
        float4 v = *(const float4*)&out[OFF_PR + (size_t)token * NE + q * 4];
        a[q*4+0] = v.x; a[q*4+1] = v.y; a[q*4+2] = v.z; a[q*4+3] = v.w;
    }

    float m = fabsf(a[0]);
    #pragma unroll
    for (int e = 1; e < 16; ++e) m = fmaxf(m, fabsf(a[e]));
    float ssum = 0.0f;
    #pragma unroll
    for (int e = 0; e < 16; ++e) { a[e] = expf(fabsf(a[e]) - m); ssum += a[e]; }
    float inv = 1.0f / ssum;
    #pragma unroll
    for (int e = 0; e < 16; ++e) a[e] = sqrtf(a[e] * inv);

    {
        int p = 0;
        #pragma unroll
        for (int i = 0; i < 16; ++i) {
            #pragma unroll
            for (int j = i + 1; j < 16; ++j) {
                float c = sh_c[p], s = sh_s[p]; ++p;
                float ai = a[i], aj = a[j];
                a[i] = c * ai - s * aj;
                a[j] = s * ai + c * aj;
            }
        }
    }

    #pragma unroll
    for (int q = 0; q < 4; ++q)
        *(float4*)&out[OFF_DEC + (size_t)token * NE + q * 4] =
            make_float4(a[q*4], a[q*4+1], a[q*4+2], a[q*4+3]);

    float pr[16];
    float s2 = 0.0f;
    #pragma unroll
    for (int e = 0; e < 16; ++e) { pr[e] = a[e] * a[e]; s2 += pr[e]; }
    float inv2 = 1.0f / fmaxf(s2, 1e-12f);
    #pragma unroll
    for (int e = 0; e < 16; ++e) pr[e] *= inv2;
    #pragma unroll
    for (int q = 0; q < 4; ++q)
        *(float4*)&out[OFF_PR + (size_t)token * NE + q * 4] =
            make_float4(pr[q*4], pr[q*4+1], pr[q*4+2], pr[q*4+3]);

    float bv = pr[0]; int bi = 0;
    #pragma unroll
    for (int e = 1; e < 16; ++e) if (pr[e] > bv) { bv = pr[e]; bi = e; }
    float sv = -1.0f; int si = 0;
    #pragma unroll
    for (int e = 0; e < 16; ++e) if (e != bi && pr[e] > sv) { sv = pr[e]; si = e; }
    float ts = fmaxf(fabsf(bv) + fabsf(sv), 1e-12f);
    out[OFF_TP + (size_t)token * 2 + 0] = bv / ts;
    out[OFF_TP + (size_t)token * 2 + 1] = sv / ts;
    out[OFF_TI + (size_t)token * 2 + 0] = (float)bi;
    out[OFF_TI + (size_t)token * 2 + 1] = (float)si;
}

extern "C" void kernel_launch(void* const* d_in, const int* in_sizes, int n_in,
                              void* d_out, int out_size, void* d_ws, size_t ws_size,
                              hipStream_t stream) {
    const float* xg  = (const float*)d_in[0];
    const float* w1a = (const float*)d_in[1];
    const float* b1a = (const float*)d_in[2];
    const float* w2a = (const float*)d_in[3];
    const float* b2a = (const float*)d_in[4];
    const float* w1p = (const float*)d_in[5];
    const float* b1p = (const float*)d_in[6];
    const float* w2p = (const float*)d_in[7];
    const float* b2p = (const float*)d_in[8];
    const float* ent = (const float*)d_in[9];
    float* out = (float*)d_out;

    if (ws_size >= (size_t)4 * 1024 * 1024) {
        _Float16* wt = (_Float16*)d_ws;
        qir_wtrans<<<1024, 256, 0, stream>>>(w1a, w1p, wt, out);
        qir_gemm<<<1024, 256, 32768, stream>>>(xg, wt, b1a, w2a, b2a,
                                               b1p, w2p, b2p, out);
    } else {
        qir_mlp<<<NTOK / 64, 512, 0, stream>>>(xg, w1a, b1a, w2a, b2a,
                                               w1p, b1p, w2p, b2p, out);
    }
    qir_epilogue<<<NTOK / 256, 256, 0, stream>>>(ent, out);
}